// Round 1
// 417.871 us; speedup vs baseline: 1.0989x; 1.0989x over previous
//
#include <hip/hip_runtime.h>
#include <hip/hip_bf16.h>

// GatedDeltaNet: B=2, T=1024, D=2048, HK=8, HV=16, DK=DV=128, KW=4
#define B_ 2
#define T_ 1024
#define D_ 2048
#define HK_ 8
#define HV_ 16
#define DK_ 128
#define DV_ 128
#define KEY_DIM_ 1024
#define VALUE_DIM_ 2048
#define CONV_DIM_ 4096
#define BT_ 2048   // B*T
#define NCH_ 16    // chunks per sequence (T/64)
#define CL_ 64     // chunk length

typedef __attribute__((ext_vector_type(8))) short short8;
typedef __attribute__((ext_vector_type(4))) float f32x4;

__device__ __forceinline__ short f2bf(float x) {
  __hip_bfloat16 h = __float2bfloat16(x);
  return *reinterpret_cast<short*>(&h);
}
__device__ __forceinline__ float bf2f(short u) {
  unsigned int x = ((unsigned int)(unsigned short)u) << 16;
  return __int_as_float(x);
}

#define GLOAD_LDS16(g, l)                                             \
  __builtin_amdgcn_global_load_lds(                                   \
      (const __attribute__((address_space(1))) void*)(g),             \
      (__attribute__((address_space(3))) void*)(l), 16, 0, 0)

// ---------------- cast f32 -> bf16 ----------------
__global__ void cast_plain(const float* __restrict__ in, short* __restrict__ out, int n4) {
  int i = blockIdx.x * blockDim.x + threadIdx.x;
  if (i < n4) {
    float4 v = ((const float4*)in)[i];
    short4 o;
    o.x = f2bf(v.x); o.y = f2bf(v.y); o.z = f2bf(v.z); o.w = f2bf(v.w);
    ((short4*)out)[i] = o;
  }
}

// ---------------- transpose + cast: W[R,C] f32 -> WT[C,R] bf16 ----------------
__global__ void transpose_cast(const float* __restrict__ W, short* __restrict__ WT, int R, int C) {
  __shared__ float tile[32][33];
  int tx = threadIdx.x, ty = threadIdx.y;
  int x = blockIdx.x * 32 + tx;
#pragma unroll
  for (int j = 0; j < 4; ++j) {
    int r = blockIdx.y * 32 + ty + j * 8;
    tile[ty + j * 8][tx] = W[(long)r * C + x];
  }
  __syncthreads();
  int ro = blockIdx.y * 32 + tx;
#pragma unroll
  for (int j = 0; j < 4; ++j) {
    int co = blockIdx.x * 32 + ty + j * 8;
    WT[(long)co * R + ro] = f2bf(tile[tx][ty + j * 8]);
  }
}

// ---------------- W_b|W_a -> Wba32[k][32] (k-major interleave) ----------------
__global__ void interleave_ba(const float* __restrict__ Wb, const float* __restrict__ Wa,
                              float* __restrict__ Wba32) {
  int i = blockIdx.x * 256 + threadIdx.x;   // D*32
  int c = i & 31, k = i >> 5;
  Wba32[i] = (c < 16) ? Wb[k * 16 + c] : Wa[k * 16 + (c - 16)];
}

// ---------------- bf16 MFMA GEMM, split output (C0 | C1 along N) -------------
// N0 and N1 are multiples of 128 so each block lands entirely in one output.
__global__ __launch_bounds__(256) void gemm128_split(const short* __restrict__ A,
                                                     const short* __restrict__ Bt,
                                                     float* __restrict__ C0,
                                                     float* __restrict__ C1,
                                                     int N0, int N1, int K) {
  __shared__ short As[128 * 32];
  __shared__ short Bs[128 * 32];
  int m0 = blockIdx.y * 128, n0 = blockIdx.x * 128;
  int tid = threadIdx.x;
  int wave = tid >> 6, lane = tid & 63;
  int wm = (wave >> 1) * 64, wn = (wave & 1) * 64;
  int quad = lane >> 4, l16 = lane & 15;
  f32x4 acc[4][4] = {};

  int ar = tid >> 2;
  int ac = (tid & 3) * 8;
  const short* Ag0 = A + (long)(m0 + ar) * K + ac;
  const short* Ag1 = A + (long)(m0 + 64 + ar) * K + ac;
  const short* Bg0 = Bt + (long)(n0 + ar) * K + ac;
  const short* Bg1 = Bt + (long)(n0 + 64 + ar) * K + ac;
  short* lA0 = As + tid * 8;
  short* lA1 = As + 64 * 32 + tid * 8;
  short* lB0 = Bs + tid * 8;
  short* lB1 = Bs + 64 * 32 + tid * 8;

  for (int k0 = 0; k0 < K; k0 += 32) {
    GLOAD_LDS16(Ag0 + k0, lA0);
    GLOAD_LDS16(Ag1 + k0, lA1);
    GLOAD_LDS16(Bg0 + k0, lB0);
    GLOAD_LDS16(Bg1 + k0, lB1);
    __syncthreads();

    short8 af[4], bf_[4];
#pragma unroll
    for (int i = 0; i < 4; ++i) af[i] = *(const short8*)(As + (wm + i * 16 + l16) * 32 + quad * 8);
#pragma unroll
    for (int j = 0; j < 4; ++j) bf_[j] = *(const short8*)(Bs + (wn + j * 16 + l16) * 32 + quad * 8);
#pragma unroll
    for (int i = 0; i < 4; ++i)
#pragma unroll
      for (int j = 0; j < 4; ++j)
        acc[i][j] = __builtin_amdgcn_mfma_f32_16x16x32_bf16(af[i], bf_[j], acc[i][j], 0, 0, 0);
    __syncthreads();
  }

  float* Cw; int ldc, cb;
  if (n0 < N0) { Cw = C0; ldc = N0; cb = n0; }
  else         { Cw = C1; ldc = N1; cb = n0 - N0; }
#pragma unroll
  for (int i = 0; i < 4; ++i)
#pragma unroll
    for (int j = 0; j < 4; ++j)
#pragma unroll
      for (int r = 0; r < 4; ++r) {
        int row = m0 + wm + i * 16 + quad * 4 + r;
        int colx = cb + wn + j * 16 + l16;
        Cw[(long)row * ldc + colx] = acc[i][j][r];
      }
}

// ---------------- bf16 MFMA GEMM, split-K=2 -> partial buffers ---------------
__global__ __launch_bounds__(256) void gemm128_ks(const short* __restrict__ A,
                                                  const short* __restrict__ Bt,
                                                  float* __restrict__ Cp,
                                                  int M, int N, int K) {
  __shared__ short As[128 * 32];
  __shared__ short Bs[128 * 32];
  int m0 = blockIdx.y * 128, n0 = blockIdx.x * 128;
  int kh = K >> 1;
  int kbeg = blockIdx.z * kh;
  int tid = threadIdx.x;
  int wave = tid >> 6, lane = tid & 63;
  int wm = (wave >> 1) * 64, wn = (wave & 1) * 64;
  int quad = lane >> 4, l16 = lane & 15;
  f32x4 acc[4][4] = {};

  int ar = tid >> 2;
  int ac = (tid & 3) * 8;
  const short* Ag0 = A + (long)(m0 + ar) * K + ac + kbeg;
  const short* Ag1 = A + (long)(m0 + 64 + ar) * K + ac + kbeg;
  const short* Bg0 = Bt + (long)(n0 + ar) * K + ac + kbeg;
  const short* Bg1 = Bt + (long)(n0 + 64 + ar) * K + ac + kbeg;
  short* lA0 = As + tid * 8;
  short* lA1 = As + 64 * 32 + tid * 8;
  short* lB0 = Bs + tid * 8;
  short* lB1 = Bs + 64 * 32 + tid * 8;

  for (int k0 = 0; k0 < kh; k0 += 32) {
    GLOAD_LDS16(Ag0 + k0, lA0);
    GLOAD_LDS16(Ag1 + k0, lA1);
    GLOAD_LDS16(Bg0 + k0, lB0);
    GLOAD_LDS16(Bg1 + k0, lB1);
    __syncthreads();

    short8 af[4], bf_[4];
#pragma unroll
    for (int i = 0; i < 4; ++i) af[i] = *(const short8*)(As + (wm + i * 16 + l16) * 32 + quad * 8);
#pragma unroll
    for (int j = 0; j < 4; ++j) bf_[j] = *(const short8*)(Bs + (wn + j * 16 + l16) * 32 + quad * 8);
#pragma unroll
    for (int i = 0; i < 4; ++i)
#pragma unroll
      for (int j = 0; j < 4; ++j)
        acc[i][j] = __builtin_amdgcn_mfma_f32_16x16x32_bf16(af[i], bf_[j], acc[i][j], 0, 0, 0);
    __syncthreads();
  }

  float* Cz = Cp + (long)blockIdx.z * M * N;
#pragma unroll
  for (int i = 0; i < 4; ++i)
#pragma unroll
    for (int j = 0; j < 4; ++j)
#pragma unroll
      for (int r = 0; r < 4; ++r) {
        int row = m0 + wm + i * 16 + quad * 4 + r;
        int colx = n0 + wn + j * 16 + l16;
        Cz[(long)row * N + colx] = acc[i][j][r];
      }
}

// ---------------- sum two split-K partials ----------------
__global__ void add2(const float* __restrict__ p0, const float* __restrict__ p1,
                     float* __restrict__ out, int n4) {
  int i = blockIdx.x * 256 + threadIdx.x;
  if (i < n4) {
    float4 a = ((const float4*)p0)[i];
    float4 b = ((const float4*)p1)[i];
    float4 o;
    o.x = a.x + b.x; o.y = a.y + b.y; o.z = a.z + b.z; o.w = a.w + b.w;
    ((float4*)out)[i] = o;
  }
}

// ---------------- beta / g projections (fp32, coalesced mini-GEMM) -----------
__global__ __launch_bounds__(256) void small_proj(const float* __restrict__ hidden,
                                                  const float* __restrict__ Wba32,
                                                  const float* __restrict__ dt_bias,
                                                  const float* __restrict__ A_log,
                                                  float* __restrict__ betaT,
                                                  float* __restrict__ gT) {
  __shared__ float red[2][32][33];
  int r0 = blockIdx.x * 2;
  int tid = threadIdx.x;
  int cg = tid & 7, s = tid >> 3;
  const f32x4* wp = (const f32x4*)Wba32 + (long)s * 64 * 8 + cg;
  const f32x4* h0 = (const f32x4*)(hidden + (long)r0 * D_ + s * 64);
  const f32x4* h1 = (const f32x4*)(hidden + (long)(r0 + 1) * D_ + s * 64);
  f32x4 a0 = {0.f, 0.f, 0.f, 0.f}, a1 = {0.f, 0.f, 0.f, 0.f};
#pragma unroll
  for (int ii = 0; ii < 16; ++ii) {
    f32x4 ha = h0[ii], hb = h1[ii];
    f32x4 w0 = wp[(ii * 4 + 0) * 8];
    f32x4 w1 = wp[(ii * 4 + 1) * 8];
    f32x4 w2 = wp[(ii * 4 + 2) * 8];
    f32x4 w3 = wp[(ii * 4 + 3) * 8];
    a0 += ha[0] * w0; a1 += hb[0] * w0;
    a0 += ha[1] * w1; a1 += hb[1] * w1;
    a0 += ha[2] * w2; a1 += hb[2] * w2;
    a0 += ha[3] * w3; a1 += hb[3] * w3;
  }
#pragma unroll
  for (int j = 0; j < 4; ++j) {
    red[0][s][cg * 4 + j] = a0[j];
    red[1][s][cg * 4 + j] = a1[j];
  }
  __syncthreads();
  if (tid < 64) {
    int row = tid >> 5, c = tid & 31;
    float t0 = 0.f, t1 = 0.f, t2 = 0.f, t3 = 0.f;
#pragma unroll
    for (int ss = 0; ss < 32; ss += 4) {
      t0 += red[row][ss][c];
      t1 += red[row][ss + 1][c];
      t2 += red[row][ss + 2][c];
      t3 += red[row][ss + 3][c];
    }
    float t = (t0 + t1) + (t2 + t3);
    int r = r0 + row;
    if (c < 16) {
      betaT[c * BT_ + r] = 1.f / (1.f + __expf(-t));
    } else {
      int hh = c - 16;
      float y = t + dt_bias[hh];
      float sp = fmaxf(y, 0.f) + log1pf(__expf(-fabsf(y)));
      gT[hh * BT_ + r] = -__expf(A_log[hh]) * sp;   // raw g (log decay)
    }
  }
}

// ---------------- depthwise causal conv (K=4) + SiLU ----------------
__global__ void conv_silu(const float* __restrict__ x, const float* __restrict__ w,
                          float* __restrict__ y) {
  int idx = blockIdx.x * 256 + threadIdx.x;
  int c = idx & (CONV_DIM_ - 1);
  int bt = idx >> 12;
  int t = bt & (T_ - 1);
  float4 wc = *(const float4*)(w + c * 4);
  const float* xp = x + (long)idx;
  float acc = wc.w * xp[0];
  if (t >= 1) acc += wc.z * xp[-CONV_DIM_];
  if (t >= 2) acc += wc.y * xp[-2 * CONV_DIM_];
  if (t >= 3) acc += wc.x * xp[-3 * CONV_DIM_];
  y[idx] = acc * (1.f / (1.f + __expf(-acc)));
}

// ---------------- q/k l2norm (+ q scale), bf16 out ----------------
__global__ __launch_bounds__(64) void qknorm(const float* __restrict__ qkv,
                                             short* __restrict__ qb, short* __restrict__ kb) {
  int bi = blockIdx.x;          // B*T*HK*2
  int which = bi & 1;
  int h = (bi >> 1) & 7;
  int bt = bi >> 4;
  int lane = threadIdx.x;
  const float* src = qkv + (long)bt * CONV_DIM_ + which * KEY_DIM_ + h * DK_;
  float2 v = *(const float2*)(src + lane * 2);
  float ss = v.x * v.x + v.y * v.y;
#pragma unroll
  for (int m = 32; m; m >>= 1) ss += __shfl_xor(ss, m, 64);
  float scale = rsqrtf(ss + 1e-6f);
  if (which == 0) scale *= 0.08838834764831845f;  // DK^-0.5
  short* dst = (which ? kb : qb) + ((long)bt * HK_ + h) * DK_;
  short2 o; o.x = f2bf(v.x * scale); o.y = f2bf(v.y * scale);
  ((short2*)dst)[lane] = o;
}

// ================= PHASE 1: per-chunk local quantities (parallel, 512 blocks)
__global__ __launch_bounds__(256, 2) void chunk_phase1(
    const short* __restrict__ qbf, const short* __restrict__ kbf,
    const float* __restrict__ qkv, const float* __restrict__ gT,
    const float* __restrict__ bT,
    short* __restrict__ Pm, short* __restrict__ GQ, short* __restrict__ KtT,
    short* __restrict__ Wneg, float* __restrict__ Ut, float* __restrict__ Gammac) {
  __shared__ float Al[64 * 64];      // 16 KB
  __shared__ float Gs[64], Gam[64], Dd[64], Bet[64], BG[64];

  int ci = blockIdx.x;
  int c = ci & 15, hv = (ci >> 4) & 15, b = ci >> 8;
  int hk = hv >> 1;
  int t0 = c * CL_;
  int tid = threadIdx.x;
  int wave = tid >> 6, lane = tid & 63, quad = lane >> 4, l16 = lane & 15;

  if (tid < 64) {
    float g = gT[(hv * B_ + b) * T_ + t0 + tid];
    float x = g;
#pragma unroll
    for (int off = 1; off < 64; off <<= 1) {
      float y = __shfl_up(x, off, 64);
      if (tid >= off) x += y;
    }
    Gs[tid] = x;
    float gm = __expf(x);
    Gam[tid] = gm;
    float Gtot = __shfl(x, 63, 64);
    Dd[tid] = __expf(Gtot - x);
    float bb = bT[(hv * B_ + b) * T_ + t0 + tid];
    Bet[tid] = bb;
    BG[tid] = bb * gm;
    if (tid == 63) Gammac[ci] = __expf(x);
  }
  __syncthreads();

  const long kbase = ((long)(b * T_ + t0) * HK_ + hk) * DK_;   // in shorts
  const int kstride = HK_ * DK_;                               // 1024

  // ---- RHS columns into registers (coalesced: lane-consecutive cols) ----
  int half = tid >> 7;        // 0 = V-columns, 1 = betaGammaK-columns
  int col = tid & 127;
  float u[64];
  {
    const float* vcol = qkv + (long)(b * T_ + t0) * CONV_DIM_ + 2 * KEY_DIM_ + hv * DV_ + col;
    const short* kcol = kbf + kbase + col;
    if (half == 0) {
#pragma unroll
      for (int r = 0; r < 64; ++r) u[r] = vcol[(long)r * CONV_DIM_];
    } else {
#pragma unroll
      for (int r = 0; r < 64; ++r) u[r] = bf2f(kcol[(long)r * kstride]);
    }
  }

  // ---- KK^T -> Al (mask s>r, scale beta_s * exp(G_s - G_r)) ----
  {
    f32x4 acc[4] = {};
#pragma unroll
    for (int kk = 0; kk < 4; ++kk) {
      short8 afr = *(const short8*)(kbf + kbase + (long)(16 * wave + l16) * kstride + kk * 32 + quad * 8);
#pragma unroll
      for (int j = 0; j < 4; ++j) {
        short8 bfr = *(const short8*)(kbf + kbase + (long)(16 * j + l16) * kstride + kk * 32 + quad * 8);
        acc[j] = __builtin_amdgcn_mfma_f32_16x16x32_bf16(afr, bfr, acc[j], 0, 0, 0);
      }
    }
#pragma unroll
    for (int j = 0; j < 4; ++j)
#pragma unroll
      for (int r = 0; r < 4; ++r) {
        int row = 16 * wave + quad * 4 + r, colx = 16 * j + l16;
        float v = 0.f;
        if (row > colx) v = Bet[row] * __expf(Gs[row] - Gs[colx]) * acc[j][r];
        Al[row * 64 + colx] = v;
      }
  }
  // ---- QK^T -> Pm (mask t>=s, scale exp(G_t - G_s)) ----
  {
    f32x4 acc[4] = {};
#pragma unroll
    for (int kk = 0; kk < 4; ++kk) {
      short8 afr = *(const short8*)(qbf + kbase + (long)(16 * wave + l16) * kstride + kk * 32 + quad * 8);
#pragma unroll
      for (int j = 0; j < 4; ++j) {
        short8 bfr = *(const short8*)(kbf + kbase + (long)(16 * j + l16) * kstride + kk * 32 + quad * 8);
        acc[j] = __builtin_amdgcn_mfma_f32_16x16x32_bf16(afr, bfr, acc[j], 0, 0, 0);
      }
    }
#pragma unroll
    for (int j = 0; j < 4; ++j)
#pragma unroll
      for (int r = 0; r < 4; ++r) {
        int row = 16 * wave + quad * 4 + r, colx = 16 * j + l16;
        float v = 0.f;
        if (row >= colx) v = __expf(Gs[row] - Gs[colx]) * acc[j][r];
        Pm[(long)ci * 4096 + row * 64 + colx] = f2bf(v);
      }
  }
  // ---- GQ[s][d] = Gam[s]*q[s][d] (coalesced short2 writes) ----
  for (int s = wave; s < 64; s += 4) {
    float gm = Gam[s];
    short2 qv = *(const short2*)(qbf + kbase + (long)s * kstride + lane * 2);
    short2 o;
    o.x = f2bf(bf2f(qv.x) * gm);
    o.y = f2bf(bf2f(qv.y) * gm);
    *(short2*)(GQ + (long)ci * 8192 + s * 128 + lane * 2) = o;
  }
  // ---- KtT[d][s] = k[s][d]*Dd[s] ----
  for (int d = wave; d < 128; d += 4) {
    float kv = bf2f(kbf[kbase + (long)lane * kstride + d]);
    KtT[(long)ci * 8192 + d * 64 + lane] = f2bf(kv * Dd[lane]);
  }
  __syncthreads();   // Al complete

  // ---- scale RHS, register-resident forward substitution ----
  if (half == 0) {
#pragma unroll
    for (int r = 0; r < 64; ++r) u[r] *= Bet[r];
  } else {
#pragma unroll
    for (int r = 0; r < 64; ++r) u[r] *= BG[r];
  }
#pragma unroll
  for (int s = 1; s < 64; ++s) {
    const float* Ar = Al + s * 64;
    float acc = 0.f;
#pragma unroll
    for (int r4 = 0; r4 + 4 <= s; r4 += 4) {
      float4 a = *(const float4*)(Ar + r4);
      acc += (a.x * u[r4] + a.y * u[r4 + 1]) + (a.z * u[r4 + 2] + a.w * u[r4 + 3]);
    }
#pragma unroll
    for (int r = (s / 4) * 4; r < s; ++r) acc += Ar[r] * u[r];
    u[s] -= acc;
  }
  // ---- write out (coalesced) ----
  if (half == 0) {
    float* up = Ut + (long)ci * 8192 + col;
#pragma unroll
    for (int s = 0; s < 64; ++s) up[s * 128] = u[s];
  } else {
    short* wp = Wneg + (long)ci * 8192 + col;
#pragma unroll
    for (int s = 0; s < 64; ++s) wp[s * 128] = f2bf(-u[s]);
  }
}

// ================= PHASE 2: state recurrence over chunks (64 blocks) =========
__global__ __launch_bounds__(256) void chunk_phase2(
    const short* __restrict__ Wneg, const float* __restrict__ Ut,
    const short* __restrict__ KtT, const float* __restrict__ Gammac,
    short* __restrict__ UTg, short* __restrict__ ScTg) {
  __shared__ short SLT[64 * 136];   // S^T half [n 64][m 128 pad 136], 17 KB
  __shared__ short ULT[64 * 72];    // U^T half [n 64][s 64 pad 72], 9 KB
  int bi = blockIdx.x >> 1;          // b*16+hv
  int n0 = (blockIdx.x & 1) * 64;    // col-half base
  int tid = threadIdx.x, wave = tid >> 6, lane = tid & 63, quad = lane >> 4, l16 = lane & 15;
  f32x4 S[2][4] = {};   // rows 32*wave+16i+quad*4, cols n0+16j+l16

  for (int ch = 0; ch < NCH_; ++ch) {
    long ci = (long)bi * NCH_ + ch;
#pragma unroll
    for (int i = 0; i < 2; ++i)
#pragma unroll
      for (int j = 0; j < 4; ++j) {
        int m0 = 32 * wave + 16 * i + quad * 4;
        int n = 16 * j + l16;
        short4 p;
        p.x = f2bf(S[i][j][0]); p.y = f2bf(S[i][j][1]);
        p.z = f2bf(S[i][j][2]); p.w = f2bf(S[i][j][3]);
        *(short4*)(SLT + n * 136 + m0) = p;
        *(short4*)(ScTg + ci * 16384 + (n0 + n) * 128 + m0) = p;
      }
    __syncthreads();
    f32x4 Ua[4];
#pragma unroll
    for (int j = 0; j < 4; ++j) {
      const float* up = Ut + ci * 8192 + (16 * wave + quad * 4) * 128 + n0 + 16 * j + l16;
#pragma unroll
      for (int r = 0; r < 4; ++r) Ua[j][r] = up[r * 128];
    }
#pragma unroll
    for (int kk = 0; kk < 4; ++kk) {
      short8 af = *(const short8*)(Wneg + ci * 8192 + (16 * wave + l16) * 128 + kk * 32 + quad * 8);
#pragma unroll
      for (int j = 0; j < 4; ++j) {
        short8 bfv = *(const short8*)(SLT + (16 * j + l16) * 136 + kk * 32 + quad * 8);
        Ua[j] = __builtin_amdgcn_mfma_f32_16x16x32_bf16(af, bfv, Ua[j], 0, 0, 0);
      }
    }
#pragma unroll
    for (int j = 0; j < 4; ++j) {
      int n = 16 * j + l16, s0q = 16 * wave + quad * 4;
      short4 p;
      p.x = f2bf(Ua[j][0]); p.y = f2bf(Ua[j][1]);
      p.z = f2bf(Ua[j][2]); p.w = f2bf(Ua[j][3]);
      *(short4*)(ULT + n * 72 + s0q) = p;
      *(short4*)(UTg + ci * 8192 + (n0 + n) * 64 + s0q) = p;
    }
    __syncthreads();
    float gc = Gammac[ci];
#pragma unroll
    for (int i = 0; i < 2; ++i)
#pragma unroll
      for (int j = 0; j < 4; ++j)
#pragma unroll
        for (int r = 0; r < 4; ++r) S[i][j][r] *= gc;
#pragma unroll
    for (int kk = 0; kk < 2; ++kk)
#pragma unroll
      for (int i = 0; i < 2; ++i) {
        short8 af = *(const short8*)(KtT + ci * 8192 + (32 * wave + 16 * i + l16) * 64 + kk * 32 + quad * 8);
#pragma unroll
        for (int j = 0; j < 4; ++j) {
          short8 bfv = *(const short8*)(ULT + (16 * j + l16) * 72 + kk * 32 + quad * 8);
          S[i][j] = __builtin_amdgcn_mfma_f32_16x16x32_bf16(af, bfv, S[i][j], 0, 0, 0);
        }
      }
    __syncthreads();
  }
}

// ================= PHASE 3: outputs + fused gated RMSNorm (512 blocks) =======
__global__ __launch_bounds__(256) void chunk_phase3(
    const short* __restrict__ GQ, const short* __restrict__ ScTg,
    const short* __restrict__ Pm, const short* __restrict__ UTg,
    const float* __restrict__ zbuf, const float* __restrict__ nw,
    short* __restrict__ obf) {
  int ci = blockIdx.x;
  int c = ci & 15, hv = (ci >> 4) & 15, b = ci >> 8;
  int t0 = c * CL_;
  int tid = threadIdx.x, wave = tid >> 6, lane = tid & 63, quad = lane >> 4, l16 = lane & 15;
  f32x4 acc[8] = {};
#pragma unroll
  for (int kk = 0; kk < 4; ++kk) {
    short8 af = *(const short8*)(GQ + (long)ci * 8192 + (16 * wave + l16) * 128 + kk * 32 + quad * 8);
#pragma unroll
    for (int j = 0; j < 8; ++j) {
      short8 bfv = *(const short8*)(ScTg + (long)ci * 16384 + (16 * j + l16) * 128 + kk * 32 + quad * 8);
      acc[j] = __builtin_amdgcn_mfma_f32_16x16x32_bf16(af, bfv, acc[j], 0, 0, 0);
    }
  }
#pragma unroll
  for (int kk = 0; kk < 2; ++kk) {
    short8 af = *(const short8*)(Pm + (long)ci * 4096 + (16 * wave + l16) * 64 + kk * 32 + quad * 8);
#pragma unroll
    for (int j = 0; j < 8; ++j) {
      short8 bfv = *(const short8*)(UTg + (long)ci * 8192 + (16 * j + l16) * 64 + kk * 32 + quad * 8);
      acc[j] = __builtin_amdgcn_mfma_f32_16x16x32_bf16(af, bfv, acc[j], 0, 0, 0);
    }
  }
  // fused gated RMSNorm * silu(z) epilogue.
  // For each output row t (= t0 + 16*wave + quad*4 + r), the 16 lanes of this
  // quad-group (l16 = 0..15) hold the full 128-wide o-row across j (col = 16j+l16).
#pragma unroll
  for (int r = 0; r < 4; ++r) {
    float ss = 0.f;
#pragma unroll
    for (int j = 0; j < 8; ++j) ss += acc[j][r] * acc[j][r];
    ss += __shfl_xor(ss, 1, 64);
    ss += __shfl_xor(ss, 2, 64);
    ss += __shfl_xor(ss, 4, 64);
    ss += __shfl_xor(ss, 8, 64);
    float scale = rsqrtf(ss * (1.f / 128.f) + 1e-6f);
    int t = t0 + 16 * wave + quad * 4 + r;
    long base = (long)(b * T_ + t) * VALUE_DIM_ + hv * DV_;
#pragma unroll
    for (int j = 0; j < 8; ++j) {
      int n = 16 * j + l16;
      float zv = zbuf[base + n];
      float sz = zv * (1.f / (1.f + __expf(-zv)));
      obf[base + n] = f2bf(acc[j][r] * scale * nw[n] * sz);
    }
  }
}

// ---------------- launcher ----------------
extern "C" void kernel_launch(void* const* d_in, const int* in_sizes, int n_in,
                              void* d_out, int out_size, void* d_ws, size_t ws_size,
                              hipStream_t stream) {
  const float* hidden  = (const float*)d_in[0];
  const float* W_qkv   = (const float*)d_in[1];
  const float* W_z     = (const float*)d_in[2];
  const float* W_b     = (const float*)d_in[3];
  const float* W_a     = (const float*)d_in[4];
  const float* conv_w  = (const float*)d_in[5];
  const float* dt_bias = (const float*)d_in[6];
  const float* A_log   = (const float*)d_in[7];
  const float* norm_w  = (const float*)d_in[8];
  const float* W_out   = (const float*)d_in[9];
  float* out = (float*)d_out;

  char* ws = (char*)d_ws;
  size_t off = 0;
  auto alloc = [&](size_t bytes) {
    void* p = ws + off;
    off += (bytes + 255) & ~(size_t)255;
    return p;
  };
  short* hidden_bf = (short*)alloc((size_t)BT_ * D_ * 2);           // 8 MB
  short* WcatT     = (short*)alloc((size_t)(CONV_DIM_ + VALUE_DIM_) * D_ * 2); // 24 MB
  short* WoutT     = (short*)alloc((size_t)D_ * VALUE_DIM_ * 2);    // 8 MB
  float* mixed     = (float*)alloc((size_t)BT_ * CONV_DIM_ * 4);    // 32 MB
  float* qkv       = (float*)alloc((size_t)BT_ * CONV_DIM_ * 4);    // 32 MB
  float* zbuf      = (float*)alloc((size_t)BT_ * VALUE_DIM_ * 4);   // 16 MB
  short* qbf       = (short*)alloc((size_t)BT_ * KEY_DIM_ * 2);     // 4 MB
  short* kbf       = (short*)alloc((size_t)BT_ * KEY_DIM_ * 2);     // 4 MB
  float* betab     = (float*)alloc((size_t)BT_ * HV_ * 4);
  float* gb        = (float*)alloc((size_t)BT_ * HV_ * 4);
  float* Wba32     = (float*)alloc((size_t)D_ * 32 * 4);            // 256 KB
  short* Wneg      = (short*)alloc((size_t)512 * 8192 * 2);         // 8 MB
  float* Ut32      = (float*)alloc((size_t)512 * 8192 * 4);         // 16 MB
  short* KtT       = (short*)alloc((size_t)512 * 8192 * 2);         // 8 MB
  short* UTg       = (short*)alloc((size_t)512 * 8192 * 2);         // 8 MB
  short* ScTg      = (short*)alloc((size_t)512 * 16384 * 2);        // 16 MB
  float* Gammac    = (float*)alloc((size_t)512 * 4);
  // aliases (into buffers dead by the time they're written):
  short* Pm   = (short*)(mixed + (size_t)BT_ * VALUE_DIM_);         // 4 MB (mixed dead after conv)
  short* GQ   = Pm + (size_t)512 * 4096;                            // 8 MB
  short* obf  = hidden_bf;          // dead after fused qkv+z GEMM
  float* Cpart = qkv;               // 32 MB; qkv dead after phase1 (split-K partials)

  dim3 tb32(32, 8);
  cast_plain<<<(BT_ * D_ / 4 + 255) / 256, 256, 0, stream>>>(hidden, hidden_bf, BT_ * D_ / 4);
  transpose_cast<<<dim3(CONV_DIM_ / 32, D_ / 32), tb32, 0, stream>>>(W_qkv, WcatT, D_, CONV_DIM_);
  transpose_cast<<<dim3(VALUE_DIM_ / 32, D_ / 32), tb32, 0, stream>>>(W_z, WcatT + (size_t)CONV_DIM_ * D_, D_, VALUE_DIM_);
  transpose_cast<<<dim3(D_ / 32, VALUE_DIM_ / 32), tb32, 0, stream>>>(W_out, WoutT, VALUE_DIM_, D_);
  interleave_ba<<<32 * D_ / 256, 256, 0, stream>>>(W_b, W_a, Wba32);

  // fused qkv + z projection: N = 6144, grid 48x16 = 768 blocks (3 blk/CU)
  gemm128_split<<<dim3((CONV_DIM_ + VALUE_DIM_) / 128, BT_ / 128), 256, 0, stream>>>(
      hidden_bf, WcatT, mixed, zbuf, CONV_DIM_, VALUE_DIM_, D_);
  small_proj<<<BT_ / 2, 256, 0, stream>>>(hidden, Wba32, dt_bias, A_log, betab, gb);
  conv_silu<<<BT_ * CONV_DIM_ / 256, 256, 0, stream>>>(mixed, conv_w, qkv);
  qknorm<<<BT_ * HK_ * 2, 64, 0, stream>>>(qkv, qbf, kbf);

  chunk_phase1<<<512, 256, 0, stream>>>(qbf, kbf, qkv, gb, betab, Pm, GQ, KtT, Wneg, Ut32, Gammac);
  chunk_phase2<<<64, 256, 0, stream>>>(Wneg, Ut32, KtT, Gammac, UTg, ScTg);
  chunk_phase3<<<512, 256, 0, stream>>>(GQ, ScTg, Pm, UTg, zbuf, norm_w, obf);

  // out projection: split-K=2 -> 512 blocks (2 blk/CU), then partial-sum
  gemm128_ks<<<dim3(D_ / 128, BT_ / 128, 2), 256, 0, stream>>>(obf, WoutT, Cpart, BT_, D_, VALUE_DIM_);
  add2<<<(BT_ * D_ / 4 + 255) / 256, 256, 0, stream>>>(Cpart, Cpart + (size_t)BT_ * D_, out, BT_ * D_ / 4);
}

// Round 2
// 375.992 us; speedup vs baseline: 1.2213x; 1.1114x over previous
//
#include <hip/hip_runtime.h>
#include <hip/hip_bf16.h>

// GatedDeltaNet: B=2, T=1024, D=2048, HK=8, HV=16, DK=DV=128, KW=4
#define B_ 2
#define T_ 1024
#define D_ 2048
#define HK_ 8
#define HV_ 16
#define DK_ 128
#define DV_ 128
#define KEY_DIM_ 1024
#define VALUE_DIM_ 2048
#define CONV_DIM_ 4096
#define BT_ 2048   // B*T
#define NCH_ 16    // chunks per sequence (T/64)
#define CL_ 64     // chunk length

typedef __attribute__((ext_vector_type(8))) short short8;
typedef __attribute__((ext_vector_type(4))) float f32x4;

__device__ __forceinline__ short f2bf(float x) {
  __hip_bfloat16 h = __float2bfloat16(x);
  return *reinterpret_cast<short*>(&h);
}
__device__ __forceinline__ float bf2f(short u) {
  unsigned int x = ((unsigned int)(unsigned short)u) << 16;
  return __int_as_float(x);
}

#define GLOAD_LDS16(g, l)                                             \
  __builtin_amdgcn_global_load_lds(                                   \
      (const __attribute__((address_space(1))) void*)(g),             \
      (__attribute__((address_space(3))) void*)(l), 16, 0, 0)

// ---------------- transpose + cast: W[R,C] f32 -> WT[C,R] bf16 ----------------
__global__ void transpose_cast(const float* __restrict__ W, short* __restrict__ WT, int R, int C) {
  __shared__ float tile[32][33];
  int tx = threadIdx.x, ty = threadIdx.y;
  int x = blockIdx.x * 32 + tx;
#pragma unroll
  for (int j = 0; j < 4; ++j) {
    int r = blockIdx.y * 32 + ty + j * 8;
    tile[ty + j * 8][tx] = W[(long)r * C + x];
  }
  __syncthreads();
  int ro = blockIdx.y * 32 + tx;
#pragma unroll
  for (int j = 0; j < 4; ++j) {
    int co = blockIdx.x * 32 + ty + j * 8;
    WT[(long)co * R + ro] = f2bf(tile[tx][ty + j * 8]);
  }
}

// ---------------- W_b|W_a -> Wba32[k][32] (k-major interleave) ----------------
__global__ void interleave_ba(const float* __restrict__ Wb, const float* __restrict__ Wa,
                              float* __restrict__ Wba32) {
  int i = blockIdx.x * 256 + threadIdx.x;   // D*32
  int c = i & 31, k = i >> 5;
  Wba32[i] = (c < 16) ? Wb[k * 16 + c] : Wa[k * 16 + (c - 16)];
}

// ---------------- bf16 MFMA GEMM, dbuf + counted vmcnt, split output ---------
// N0, N1 multiples of 128 so each block lands entirely in one output.
__global__ __launch_bounds__(256) void gemm128_split(const short* __restrict__ A,
                                                     const short* __restrict__ Bt,
                                                     float* __restrict__ C0,
                                                     float* __restrict__ C1,
                                                     int N0, int N1, int K) {
  __shared__ short As[2][128 * 32];
  __shared__ short Bs[2][128 * 32];
  int m0 = blockIdx.y * 128, n0 = blockIdx.x * 128;
  int tid = threadIdx.x;
  int wave = tid >> 6, lane = tid & 63;
  int wm = (wave >> 1) * 64, wn = (wave & 1) * 64;
  int quad = lane >> 4, l16 = lane & 15;
  f32x4 acc[4][4] = {};

  int ar = tid >> 2;
  int ac = (tid & 3) * 8;
  const short* Ag0 = A + (long)(m0 + ar) * K + ac;
  const short* Ag1 = A + (long)(m0 + 64 + ar) * K + ac;
  const short* Bg0 = Bt + (long)(n0 + ar) * K + ac;
  const short* Bg1 = Bt + (long)(n0 + 64 + ar) * K + ac;
  int NT = K >> 5;

#define STAGE_(t, c)                                  \
  do {                                                \
    GLOAD_LDS16(Ag0 + (t) * 32, As[c] + tid * 8);     \
    GLOAD_LDS16(Ag1 + (t) * 32, As[c] + 64 * 32 + tid * 8); \
    GLOAD_LDS16(Bg0 + (t) * 32, Bs[c] + tid * 8);     \
    GLOAD_LDS16(Bg1 + (t) * 32, Bs[c] + 64 * 32 + tid * 8); \
  } while (0)

  STAGE_(0, 0);
  STAGE_(1, 1);

  for (int t = 0; t < NT; ++t) {
    int c = t & 1;
    if (t + 1 < NT) {
      asm volatile("s_waitcnt vmcnt(4)" ::: "memory");   // tile t landed, t+1 in flight
    } else {
      asm volatile("s_waitcnt vmcnt(0)" ::: "memory");
    }
    __builtin_amdgcn_s_barrier();
    __builtin_amdgcn_sched_barrier(0);

    short8 af[4], bf_[4];
#pragma unroll
    for (int i = 0; i < 4; ++i) af[i] = *(const short8*)(As[c] + (wm + i * 16 + l16) * 32 + quad * 8);
#pragma unroll
    for (int j = 0; j < 4; ++j) bf_[j] = *(const short8*)(Bs[c] + (wn + j * 16 + l16) * 32 + quad * 8);
#pragma unroll
    for (int i = 0; i < 4; ++i)
#pragma unroll
      for (int j = 0; j < 4; ++j)
        acc[i][j] = __builtin_amdgcn_mfma_f32_16x16x32_bf16(af[i], bf_[j], acc[i][j], 0, 0, 0);

    __builtin_amdgcn_sched_barrier(0);
    __builtin_amdgcn_s_barrier();
    if (t + 2 < NT) STAGE_(t + 2, c);
  }

  float* Cw; int ldc, cb;
  if (n0 < N0) { Cw = C0; ldc = N0; cb = n0; }
  else         { Cw = C1; ldc = N1; cb = n0 - N0; }
#pragma unroll
  for (int i = 0; i < 4; ++i)
#pragma unroll
    for (int j = 0; j < 4; ++j)
#pragma unroll
      for (int r = 0; r < 4; ++r) {
        int row = m0 + wm + i * 16 + quad * 4 + r;
        int colx = cb + wn + j * 16 + l16;
        Cw[(long)row * ldc + colx] = acc[i][j][r];
      }
#undef STAGE_
}

// ---------------- bf16 MFMA GEMM, split-K=2, dbuf + counted vmcnt ------------
__global__ __launch_bounds__(256) void gemm128_ks(const short* __restrict__ A,
                                                  const short* __restrict__ Bt,
                                                  float* __restrict__ Cp,
                                                  int M, int N, int K) {
  __shared__ short As[2][128 * 32];
  __shared__ short Bs[2][128 * 32];
  int m0 = blockIdx.y * 128, n0 = blockIdx.x * 128;
  int kh = K >> 1;
  int kbeg = blockIdx.z * kh;
  int tid = threadIdx.x;
  int wave = tid >> 6, lane = tid & 63;
  int wm = (wave >> 1) * 64, wn = (wave & 1) * 64;
  int quad = lane >> 4, l16 = lane & 15;
  f32x4 acc[4][4] = {};

  int ar = tid >> 2;
  int ac = (tid & 3) * 8;
  const short* Ag0 = A + (long)(m0 + ar) * K + ac + kbeg;
  const short* Ag1 = A + (long)(m0 + 64 + ar) * K + ac + kbeg;
  const short* Bg0 = Bt + (long)(n0 + ar) * K + ac + kbeg;
  const short* Bg1 = Bt + (long)(n0 + 64 + ar) * K + ac + kbeg;
  int NT = kh >> 5;

#define STAGE_(t, c)                                  \
  do {                                                \
    GLOAD_LDS16(Ag0 + (t) * 32, As[c] + tid * 8);     \
    GLOAD_LDS16(Ag1 + (t) * 32, As[c] + 64 * 32 + tid * 8); \
    GLOAD_LDS16(Bg0 + (t) * 32, Bs[c] + tid * 8);     \
    GLOAD_LDS16(Bg1 + (t) * 32, Bs[c] + 64 * 32 + tid * 8); \
  } while (0)

  STAGE_(0, 0);
  STAGE_(1, 1);

  for (int t = 0; t < NT; ++t) {
    int c = t & 1;
    if (t + 1 < NT) {
      asm volatile("s_waitcnt vmcnt(4)" ::: "memory");
    } else {
      asm volatile("s_waitcnt vmcnt(0)" ::: "memory");
    }
    __builtin_amdgcn_s_barrier();
    __builtin_amdgcn_sched_barrier(0);

    short8 af[4], bf_[4];
#pragma unroll
    for (int i = 0; i < 4; ++i) af[i] = *(const short8*)(As[c] + (wm + i * 16 + l16) * 32 + quad * 8);
#pragma unroll
    for (int j = 0; j < 4; ++j) bf_[j] = *(const short8*)(Bs[c] + (wn + j * 16 + l16) * 32 + quad * 8);
#pragma unroll
    for (int i = 0; i < 4; ++i)
#pragma unroll
      for (int j = 0; j < 4; ++j)
        acc[i][j] = __builtin_amdgcn_mfma_f32_16x16x32_bf16(af[i], bf_[j], acc[i][j], 0, 0, 0);

    __builtin_amdgcn_sched_barrier(0);
    __builtin_amdgcn_s_barrier();
    if (t + 2 < NT) STAGE_(t + 2, c);
  }

  float* Cz = Cp + (long)blockIdx.z * M * N;
#pragma unroll
  for (int i = 0; i < 4; ++i)
#pragma unroll
    for (int j = 0; j < 4; ++j)
#pragma unroll
      for (int r = 0; r < 4; ++r) {
        int row = m0 + wm + i * 16 + quad * 4 + r;
        int colx = n0 + wn + j * 16 + l16;
        Cz[(long)row * N + colx] = acc[i][j][r];
      }
#undef STAGE_
}

// ---------------- sum two split-K partials ----------------
__global__ void add2(const float* __restrict__ p0, const float* __restrict__ p1,
                     float* __restrict__ out, int n4) {
  int i = blockIdx.x * 256 + threadIdx.x;
  if (i < n4) {
    float4 a = ((const float4*)p0)[i];
    float4 b = ((const float4*)p1)[i];
    float4 o;
    o.x = a.x + b.x; o.y = a.y + b.y; o.z = a.z + b.z; o.w = a.w + b.w;
    ((float4*)out)[i] = o;
  }
}

// ---------------- beta / g projections + fused hidden bf16 cast --------------
__global__ __launch_bounds__(256) void small_proj(const float* __restrict__ hidden,
                                                  const float* __restrict__ Wba32,
                                                  const float* __restrict__ dt_bias,
                                                  const float* __restrict__ A_log,
                                                  float* __restrict__ betaT,
                                                  float* __restrict__ gT,
                                                  short* __restrict__ hbf) {
  __shared__ float red[2][32][33];
  int r0 = blockIdx.x * 2;
  int tid = threadIdx.x;
  int cg = tid & 7, s = tid >> 3;
  const f32x4* wp = (const f32x4*)Wba32 + (long)s * 64 * 8 + cg;
  const f32x4* h0 = (const f32x4*)(hidden + (long)r0 * D_ + s * 64);
  const f32x4* h1 = (const f32x4*)(hidden + (long)(r0 + 1) * D_ + s * 64);
  f32x4 a0 = {0.f, 0.f, 0.f, 0.f}, a1 = {0.f, 0.f, 0.f, 0.f};
#pragma unroll
  for (int ii = 0; ii < 16; ++ii) {
    f32x4 ha = h0[ii], hb = h1[ii];
    f32x4 w0 = wp[(ii * 4 + 0) * 8];
    f32x4 w1 = wp[(ii * 4 + 1) * 8];
    f32x4 w2 = wp[(ii * 4 + 2) * 8];
    f32x4 w3 = wp[(ii * 4 + 3) * 8];
    a0 += ha[0] * w0; a1 += hb[0] * w0;
    a0 += ha[1] * w1; a1 += hb[1] * w1;
    a0 += ha[2] * w2; a1 += hb[2] * w2;
    a0 += ha[3] * w3; a1 += hb[3] * w3;
  }
#pragma unroll
  for (int j = 0; j < 4; ++j) {
    red[0][s][cg * 4 + j] = a0[j];
    red[1][s][cg * 4 + j] = a1[j];
  }
  // fused bf16 cast of hidden rows r0, r0+1 (L1-hot re-reads, coalesced 16B/lane)
  {
    int colb = s * 64 + cg * 8;
    const float* p0 = hidden + (long)r0 * D_ + colb;
    const float* p1 = p0 + D_;
    float4 x0 = *(const float4*)(p0);
    float4 x1 = *(const float4*)(p0 + 4);
    float4 y0 = *(const float4*)(p1);
    float4 y1 = *(const float4*)(p1 + 4);
    short8 o0, o1;
    o0[0] = f2bf(x0.x); o0[1] = f2bf(x0.y); o0[2] = f2bf(x0.z); o0[3] = f2bf(x0.w);
    o0[4] = f2bf(x1.x); o0[5] = f2bf(x1.y); o0[6] = f2bf(x1.z); o0[7] = f2bf(x1.w);
    o1[0] = f2bf(y0.x); o1[1] = f2bf(y0.y); o1[2] = f2bf(y0.z); o1[3] = f2bf(y0.w);
    o1[4] = f2bf(y1.x); o1[5] = f2bf(y1.y); o1[6] = f2bf(y1.z); o1[7] = f2bf(y1.w);
    *(short8*)(hbf + (long)r0 * D_ + colb) = o0;
    *(short8*)(hbf + (long)(r0 + 1) * D_ + colb) = o1;
  }
  __syncthreads();
  if (tid < 64) {
    int row = tid >> 5, c = tid & 31;
    float t0 = 0.f, t1 = 0.f, t2 = 0.f, t3 = 0.f;
#pragma unroll
    for (int ss = 0; ss < 32; ss += 4) {
      t0 += red[row][ss][c];
      t1 += red[row][ss + 1][c];
      t2 += red[row][ss + 2][c];
      t3 += red[row][ss + 3][c];
    }
    float t = (t0 + t1) + (t2 + t3);
    int r = r0 + row;
    if (c < 16) {
      betaT[c * BT_ + r] = 1.f / (1.f + __expf(-t));
    } else {
      int hh = c - 16;
      float y = t + dt_bias[hh];
      float sp = fmaxf(y, 0.f) + log1pf(__expf(-fabsf(y)));
      gT[hh * BT_ + r] = -__expf(A_log[hh]) * sp;   // raw g (log decay)
    }
  }
}

// ---------------- depthwise causal conv (K=4) + SiLU ----------------
__global__ void conv_silu(const float* __restrict__ x, const float* __restrict__ w,
                          float* __restrict__ y) {
  int idx = blockIdx.x * 256 + threadIdx.x;
  int c = idx & (CONV_DIM_ - 1);
  int bt = idx >> 12;
  int t = bt & (T_ - 1);
  float4 wc = *(const float4*)(w + c * 4);
  const float* xp = x + (long)idx;
  float acc = wc.w * xp[0];
  if (t >= 1) acc += wc.z * xp[-CONV_DIM_];
  if (t >= 2) acc += wc.y * xp[-2 * CONV_DIM_];
  if (t >= 3) acc += wc.x * xp[-3 * CONV_DIM_];
  y[idx] = acc * (1.f / (1.f + __expf(-acc)));
}

// ---------------- q/k l2norm (+ q scale), bf16 out ----------------
__global__ __launch_bounds__(64) void qknorm(const float* __restrict__ qkv,
                                             short* __restrict__ qb, short* __restrict__ kb) {
  int bi = blockIdx.x;          // B*T*HK*2
  int which = bi & 1;
  int h = (bi >> 1) & 7;
  int bt = bi >> 4;
  int lane = threadIdx.x;
  const float* src = qkv + (long)bt * CONV_DIM_ + which * KEY_DIM_ + h * DK_;
  float2 v = *(const float2*)(src + lane * 2);
  float ss = v.x * v.x + v.y * v.y;
#pragma unroll
  for (int m = 32; m; m >>= 1) ss += __shfl_xor(ss, m, 64);
  float scale = rsqrtf(ss + 1e-6f);
  if (which == 0) scale *= 0.08838834764831845f;  // DK^-0.5
  short* dst = (which ? kb : qb) + ((long)bt * HK_ + h) * DK_;
  short2 o; o.x = f2bf(v.x * scale); o.y = f2bf(v.y * scale);
  ((short2*)dst)[lane] = o;
}

// ================= PHASE 1: per-chunk local quantities (parallel, 512 blocks)
__global__ __launch_bounds__(256, 2) void chunk_phase1(
    const short* __restrict__ qbf, const short* __restrict__ kbf,
    const float* __restrict__ qkv, const float* __restrict__ gT,
    const float* __restrict__ bT,
    short* __restrict__ Pm, short* __restrict__ GQ, short* __restrict__ KtT,
    short* __restrict__ Wneg, float* __restrict__ Ut, float* __restrict__ Gammac) {
  __shared__ float Al[64 * 64];      // 16 KB
  __shared__ float Gs[64], Gam[64], Dd[64], Bet[64], BG[64];

  int ci = blockIdx.x;
  int c = ci & 15, hv = (ci >> 4) & 15, b = ci >> 8;
  int hk = hv >> 1;
  int t0 = c * CL_;
  int tid = threadIdx.x;
  int wave = tid >> 6, lane = tid & 63, quad = lane >> 4, l16 = lane & 15;

  if (tid < 64) {
    float g = gT[(hv * B_ + b) * T_ + t0 + tid];
    float x = g;
#pragma unroll
    for (int off = 1; off < 64; off <<= 1) {
      float y = __shfl_up(x, off, 64);
      if (tid >= off) x += y;
    }
    Gs[tid] = x;
    float gm = __expf(x);
    Gam[tid] = gm;
    float Gtot = __shfl(x, 63, 64);
    Dd[tid] = __expf(Gtot - x);
    float bb = bT[(hv * B_ + b) * T_ + t0 + tid];
    Bet[tid] = bb;
    BG[tid] = bb * gm;
    if (tid == 63) Gammac[ci] = __expf(x);
  }
  __syncthreads();

  const long kbase = ((long)(b * T_ + t0) * HK_ + hk) * DK_;   // in shorts
  const int kstride = HK_ * DK_;                               // 1024

  // ---- RHS columns into registers (coalesced: lane-consecutive cols) ----
  int half = tid >> 7;        // 0 = V-columns, 1 = betaGammaK-columns
  int col = tid & 127;
  float u[64];
  {
    const float* vcol = qkv + (long)(b * T_ + t0) * CONV_DIM_ + 2 * KEY_DIM_ + hv * DV_ + col;
    const short* kcol = kbf + kbase + col;
    if (half == 0) {
#pragma unroll
      for (int r = 0; r < 64; ++r) u[r] = vcol[(long)r * CONV_DIM_];
    } else {
#pragma unroll
      for (int r = 0; r < 64; ++r) u[r] = bf2f(kcol[(long)r * kstride]);
    }
  }

  // ---- KK^T -> Al (mask s>r, scale beta_s * exp(G_s - G_r)) ----
  {
    f32x4 acc[4] = {};
#pragma unroll
    for (int kk = 0; kk < 4; ++kk) {
      short8 afr = *(const short8*)(kbf + kbase + (long)(16 * wave + l16) * kstride + kk * 32 + quad * 8);
#pragma unroll
      for (int j = 0; j < 4; ++j) {
        short8 bfr = *(const short8*)(kbf + kbase + (long)(16 * j + l16) * kstride + kk * 32 + quad * 8);
        acc[j] = __builtin_amdgcn_mfma_f32_16x16x32_bf16(afr, bfr, acc[j], 0, 0, 0);
      }
    }
#pragma unroll
    for (int j = 0; j < 4; ++j)
#pragma unroll
      for (int r = 0; r < 4; ++r) {
        int row = 16 * wave + quad * 4 + r, colx = 16 * j + l16;
        float v = 0.f;
        if (row > colx) v = Bet[row] * __expf(Gs[row] - Gs[colx]) * acc[j][r];
        Al[row * 64 + colx] = v;
      }
  }
  // ---- QK^T -> Pm (mask t>=s, scale exp(G_t - G_s)) ----
  {
    f32x4 acc[4] = {};
#pragma unroll
    for (int kk = 0; kk < 4; ++kk) {
      short8 afr = *(const short8*)(qbf + kbase + (long)(16 * wave + l16) * kstride + kk * 32 + quad * 8);
#pragma unroll
      for (int j = 0; j < 4; ++j) {
        short8 bfr = *(const short8*)(kbf + kbase + (long)(16 * j + l16) * kstride + kk * 32 + quad * 8);
        acc[j] = __builtin_amdgcn_mfma_f32_16x16x32_bf16(afr, bfr, acc[j], 0, 0, 0);
      }
    }
#pragma unroll
    for (int j = 0; j < 4; ++j)
#pragma unroll
      for (int r = 0; r < 4; ++r) {
        int row = 16 * wave + quad * 4 + r, colx = 16 * j + l16;
        float v = 0.f;
        if (row >= colx) v = __expf(Gs[row] - Gs[colx]) * acc[j][r];
        Pm[(long)ci * 4096 + row * 64 + colx] = f2bf(v);
      }
  }
  // ---- GQ[s][d] = Gam[s]*q[s][d] (coalesced short2 writes) ----
  for (int s = wave; s < 64; s += 4) {
    float gm = Gam[s];
    short2 qv = *(const short2*)(qbf + kbase + (long)s * kstride + lane * 2);
    short2 o;
    o.x = f2bf(bf2f(qv.x) * gm);
    o.y = f2bf(bf2f(qv.y) * gm);
    *(short2*)(GQ + (long)ci * 8192 + s * 128 + lane * 2) = o;
  }
  // ---- KtT[d][s] = k[s][d]*Dd[s] ----
  for (int d = wave; d < 128; d += 4) {
    float kv = bf2f(kbf[kbase + (long)lane * kstride + d]);
    KtT[(long)ci * 8192 + d * 64 + lane] = f2bf(kv * Dd[lane]);
  }
  __syncthreads();   // Al complete

  // ---- scale RHS, register-resident forward substitution ----
  if (half == 0) {
#pragma unroll
    for (int r = 0; r < 64; ++r) u[r] *= Bet[r];
  } else {
#pragma unroll
    for (int r = 0; r < 64; ++r) u[r] *= BG[r];
  }
#pragma unroll
  for (int s = 1; s < 64; ++s) {
    const float* Ar = Al + s * 64;
    float acc = 0.f;
#pragma unroll
    for (int r4 = 0; r4 + 4 <= s; r4 += 4) {
      float4 a = *(const float4*)(Ar + r4);
      acc += (a.x * u[r4] + a.y * u[r4 + 1]) + (a.z * u[r4 + 2] + a.w * u[r4 + 3]);
    }
#pragma unroll
    for (int r = (s / 4) * 4; r < s; ++r) acc += Ar[r] * u[r];
    u[s] -= acc;
  }
  // ---- write out (coalesced) ----
  if (half == 0) {
    float* up = Ut + (long)ci * 8192 + col;
#pragma unroll
    for (int s = 0; s < 64; ++s) up[s * 128] = u[s];
  } else {
    short* wp = Wneg + (long)ci * 8192 + col;
#pragma unroll
    for (int s = 0; s < 64; ++s) wp[s * 128] = f2bf(-u[s]);
  }
}

// ================= PHASE 2: state recurrence over chunks (256 blocks) ========
// Each block owns a 16-col slice of one (b,hv) state; next-chunk operands are
// software-pipelined into registers so global latency hides under MFMA+barriers.
__global__ __launch_bounds__(256) void chunk_phase2(
    const short* __restrict__ Wneg, const float* __restrict__ Ut,
    const short* __restrict__ KtT, const float* __restrict__ Gammac,
    short* __restrict__ UTg, short* __restrict__ ScTg) {
  __shared__ short SLT[16 * 136];   // S^T slice [n 16][m 128 pad 136]
  __shared__ short ULT[16 * 72];    // U'^T slice [n 16][s 64 pad 72]
  int bi = blockIdx.x >> 3;          // b*16+hv
  int n0 = (blockIdx.x & 7) * 16;    // col-slice base
  int tid = threadIdx.x, wave = tid >> 6, lane = tid & 63, quad = lane >> 4, l16 = lane & 15;
  f32x4 S2[2] = {};   // rows 32*wave+16i+quad*4+r, col n0+l16

  long ci0 = (long)bi * NCH_;
  // preload chunk-0 operands
  short8 Wr[4]; f32x4 Ur; short8 Kr[2][2];
  {
    long ci = ci0;
#pragma unroll
    for (int kk = 0; kk < 4; ++kk)
      Wr[kk] = *(const short8*)(Wneg + ci * 8192 + (16 * wave + l16) * 128 + kk * 32 + quad * 8);
    const float* up = Ut + ci * 8192 + (16 * wave + quad * 4) * 128 + n0 + l16;
#pragma unroll
    for (int r = 0; r < 4; ++r) Ur[r] = up[r * 128];
#pragma unroll
    for (int kk = 0; kk < 2; ++kk)
#pragma unroll
      for (int i = 0; i < 2; ++i)
        Kr[kk][i] = *(const short8*)(KtT + ci * 8192 + (32 * wave + 16 * i + l16) * 64 + kk * 32 + quad * 8);
  }

  for (int ch = 0; ch < NCH_; ++ch) {
    long ci = ci0 + ch;
    // 1. write S^T slice to LDS + global
#pragma unroll
    for (int i = 0; i < 2; ++i) {
      int m0 = 32 * wave + 16 * i + quad * 4;
      short4 p;
      p.x = f2bf(S2[i][0]); p.y = f2bf(S2[i][1]);
      p.z = f2bf(S2[i][2]); p.w = f2bf(S2[i][3]);
      *(short4*)(SLT + l16 * 136 + m0) = p;
      *(short4*)(ScTg + ci * 16384 + (n0 + l16) * 128 + m0) = p;
    }
    // prefetch next-chunk operands into registers (overlaps barriers + MFMA)
    short8 Wn[4]; f32x4 Un; short8 Kn[2][2];
    if (ch + 1 < NCH_) {
      long cj = ci + 1;
#pragma unroll
      for (int kk = 0; kk < 4; ++kk)
        Wn[kk] = *(const short8*)(Wneg + cj * 8192 + (16 * wave + l16) * 128 + kk * 32 + quad * 8);
      const float* up = Ut + cj * 8192 + (16 * wave + quad * 4) * 128 + n0 + l16;
#pragma unroll
      for (int r = 0; r < 4; ++r) Un[r] = up[r * 128];
#pragma unroll
      for (int kk = 0; kk < 2; ++kk)
#pragma unroll
        for (int i = 0; i < 2; ++i)
          Kn[kk][i] = *(const short8*)(KtT + cj * 8192 + (32 * wave + 16 * i + l16) * 64 + kk * 32 + quad * 8);
    }
    __syncthreads();
    // 2. U' = U - W @ S^T  (contraction over m=128)
    f32x4 Ua = Ur;
#pragma unroll
    for (int kk = 0; kk < 4; ++kk) {
      short8 bfv = *(const short8*)(SLT + l16 * 136 + kk * 32 + quad * 8);
      Ua = __builtin_amdgcn_mfma_f32_16x16x32_bf16(Wr[kk], bfv, Ua, 0, 0, 0);
    }
    {
      int s0 = 16 * wave + quad * 4;
      short4 p;
      p.x = f2bf(Ua[0]); p.y = f2bf(Ua[1]); p.z = f2bf(Ua[2]); p.w = f2bf(Ua[3]);
      *(short4*)(ULT + l16 * 72 + s0) = p;
      *(short4*)(UTg + ci * 8192 + (n0 + l16) * 64 + s0) = p;
    }
    __syncthreads();
    // 3. S = S*gamma + KtT @ U'^T  (contraction over s=64)
    float gc = Gammac[ci];
#pragma unroll
    for (int i = 0; i < 2; ++i)
#pragma unroll
      for (int r = 0; r < 4; ++r) S2[i][r] *= gc;
#pragma unroll
    for (int kk = 0; kk < 2; ++kk) {
      short8 bfv = *(const short8*)(ULT + l16 * 72 + kk * 32 + quad * 8);
#pragma unroll
      for (int i = 0; i < 2; ++i)
        S2[i] = __builtin_amdgcn_mfma_f32_16x16x32_bf16(Kr[kk][i], bfv, S2[i], 0, 0, 0);
    }
    __syncthreads();
    if (ch + 1 < NCH_) {
#pragma unroll
      for (int kk = 0; kk < 4; ++kk) Wr[kk] = Wn[kk];
      Ur = Un;
#pragma unroll
      for (int kk = 0; kk < 2; ++kk)
#pragma unroll
        for (int i = 0; i < 2; ++i) Kr[kk][i] = Kn[kk][i];
    }
  }
}

// ================= PHASE 3: outputs + fused gated RMSNorm (512 blocks) =======
__global__ __launch_bounds__(256) void chunk_phase3(
    const short* __restrict__ GQ, const short* __restrict__ ScTg,
    const short* __restrict__ Pm, const short* __restrict__ UTg,
    const float* __restrict__ zbuf, const float* __restrict__ nw,
    short* __restrict__ obf) {
  int ci = blockIdx.x;
  int c = ci & 15, hv = (ci >> 4) & 15, b = ci >> 8;
  int t0 = c * CL_;
  int tid = threadIdx.x, wave = tid >> 6, lane = tid & 63, quad = lane >> 4, l16 = lane & 15;
  f32x4 acc[8] = {};
#pragma unroll
  for (int kk = 0; kk < 4; ++kk) {
    short8 af = *(const short8*)(GQ + (long)ci * 8192 + (16 * wave + l16) * 128 + kk * 32 + quad * 8);
#pragma unroll
    for (int j = 0; j < 8; ++j) {
      short8 bfv = *(const short8*)(ScTg + (long)ci * 16384 + (16 * j + l16) * 128 + kk * 32 + quad * 8);
      acc[j] = __builtin_amdgcn_mfma_f32_16x16x32_bf16(af, bfv, acc[j], 0, 0, 0);
    }
  }
#pragma unroll
  for (int kk = 0; kk < 2; ++kk) {
    short8 af = *(const short8*)(Pm + (long)ci * 4096 + (16 * wave + l16) * 64 + kk * 32 + quad * 8);
#pragma unroll
    for (int j = 0; j < 8; ++j) {
      short8 bfv = *(const short8*)(UTg + (long)ci * 8192 + (16 * j + l16) * 64 + kk * 32 + quad * 8);
      acc[j] = __builtin_amdgcn_mfma_f32_16x16x32_bf16(af, bfv, acc[j], 0, 0, 0);
    }
  }
  // fused gated RMSNorm * silu(z) epilogue.
#pragma unroll
  for (int r = 0; r < 4; ++r) {
    float ss = 0.f;
#pragma unroll
    for (int j = 0; j < 8; ++j) ss += acc[j][r] * acc[j][r];
    ss += __shfl_xor(ss, 1, 64);
    ss += __shfl_xor(ss, 2, 64);
    ss += __shfl_xor(ss, 4, 64);
    ss += __shfl_xor(ss, 8, 64);
    float scale = rsqrtf(ss * (1.f / 128.f) + 1e-6f);
    int t = t0 + 16 * wave + quad * 4 + r;
    long base = (long)(b * T_ + t) * VALUE_DIM_ + hv * DV_;
#pragma unroll
    for (int j = 0; j < 8; ++j) {
      int n = 16 * j + l16;
      float zv = zbuf[base + n];
      float sz = zv * (1.f / (1.f + __expf(-zv)));
      obf[base + n] = f2bf(acc[j][r] * scale * nw[n] * sz);
    }
  }
}

// ---------------- launcher ----------------
extern "C" void kernel_launch(void* const* d_in, const int* in_sizes, int n_in,
                              void* d_out, int out_size, void* d_ws, size_t ws_size,
                              hipStream_t stream) {
  const float* hidden  = (const float*)d_in[0];
  const float* W_qkv   = (const float*)d_in[1];
  const float* W_z     = (const float*)d_in[2];
  const float* W_b     = (const float*)d_in[3];
  const float* W_a     = (const float*)d_in[4];
  const float* conv_w  = (const float*)d_in[5];
  const float* dt_bias = (const float*)d_in[6];
  const float* A_log   = (const float*)d_in[7];
  const float* norm_w  = (const float*)d_in[8];
  const float* W_out   = (const float*)d_in[9];
  float* out = (float*)d_out;

  char* ws = (char*)d_ws;
  size_t off = 0;
  auto alloc = [&](size_t bytes) {
    void* p = ws + off;
    off += (bytes + 255) & ~(size_t)255;
    return p;
  };
  short* hidden_bf = (short*)alloc((size_t)BT_ * D_ * 2);           // 8 MB
  short* WcatT     = (short*)alloc((size_t)(CONV_DIM_ + VALUE_DIM_) * D_ * 2); // 24 MB
  short* WoutT     = (short*)alloc((size_t)D_ * VALUE_DIM_ * 2);    // 8 MB
  float* mixed     = (float*)alloc((size_t)BT_ * CONV_DIM_ * 4);    // 32 MB
  float* qkv       = (float*)alloc((size_t)BT_ * CONV_DIM_ * 4);    // 32 MB
  float* zbuf      = (float*)alloc((size_t)BT_ * VALUE_DIM_ * 4);   // 16 MB
  short* qbf       = (short*)alloc((size_t)BT_ * KEY_DIM_ * 2);     // 4 MB
  short* kbf       = (short*)alloc((size_t)BT_ * KEY_DIM_ * 2);     // 4 MB
  float* betab     = (float*)alloc((size_t)BT_ * HV_ * 4);
  float* gb        = (float*)alloc((size_t)BT_ * HV_ * 4);
  float* Wba32     = (float*)alloc((size_t)D_ * 32 * 4);            // 256 KB
  short* Wneg      = (short*)alloc((size_t)512 * 8192 * 2);         // 8 MB
  float* Ut32      = (float*)alloc((size_t)512 * 8192 * 4);         // 16 MB
  short* KtT       = (short*)alloc((size_t)512 * 8192 * 2);         // 8 MB
  short* UTg       = (short*)alloc((size_t)512 * 8192 * 2);         // 8 MB
  short* ScTg      = (short*)alloc((size_t)512 * 16384 * 2);        // 16 MB
  float* Gammac    = (float*)alloc((size_t)512 * 4);
  // aliases (into buffers dead by the time they're written):
  short* Pm   = (short*)(mixed + (size_t)BT_ * VALUE_DIM_);         // 4 MB (mixed dead after conv)
  short* GQ   = Pm + (size_t)512 * 4096;                            // 8 MB
  short* obf  = hidden_bf;          // dead after fused qkv+z GEMM
  float* Cpart = qkv;               // 32 MB; qkv dead after phase1 (split-K partials)

  dim3 tb32(32, 8);
  transpose_cast<<<dim3(CONV_DIM_ / 32, D_ / 32), tb32, 0, stream>>>(W_qkv, WcatT, D_, CONV_DIM_);
  transpose_cast<<<dim3(VALUE_DIM_ / 32, D_ / 32), tb32, 0, stream>>>(W_z, WcatT + (size_t)CONV_DIM_ * D_, D_, VALUE_DIM_);
  transpose_cast<<<dim3(D_ / 32, VALUE_DIM_ / 32), tb32, 0, stream>>>(W_out, WoutT, VALUE_DIM_, D_);
  interleave_ba<<<32 * D_ / 256, 256, 0, stream>>>(W_b, W_a, Wba32);

  // beta/g projections + fused hidden bf16 cast (must precede the GEMM)
  small_proj<<<BT_ / 2, 256, 0, stream>>>(hidden, Wba32, dt_bias, A_log, betab, gb, hidden_bf);

  // fused qkv + z projection: N = 6144, grid 48x16 = 768 blocks (3 blk/CU)
  gemm128_split<<<dim3((CONV_DIM_ + VALUE_DIM_) / 128, BT_ / 128), 256, 0, stream>>>(
      hidden_bf, WcatT, mixed, zbuf, CONV_DIM_, VALUE_DIM_, D_);
  conv_silu<<<BT_ * CONV_DIM_ / 256, 256, 0, stream>>>(mixed, conv_w, qkv);
  qknorm<<<BT_ * HK_ * 2, 64, 0, stream>>>(qkv, qbf, kbf);

  chunk_phase1<<<512, 256, 0, stream>>>(qbf, kbf, qkv, gb, betab, Pm, GQ, KtT, Wneg, Ut32, Gammac);
  chunk_phase2<<<256, 256, 0, stream>>>(Wneg, Ut32, KtT, Gammac, UTg, ScTg);
  chunk_phase3<<<512, 256, 0, stream>>>(GQ, ScTg, Pm, UTg, zbuf, norm_w, obf);

  // out projection: split-K=2 -> 512 blocks (2 blk/CU), then partial-sum
  gemm128_ks<<<dim3(D_ / 128, BT_ / 128, 2), 256, 0, stream>>>(obf, WoutT, Cpart, BT_, D_, VALUE_DIM_);
  add2<<<(BT_ * D_ / 4 + 255) / 256, 256, 0, stream>>>(Cpart, Cpart + (size_t)BT_ * D_, out, BT_ * D_ / 4);
}